// Round 1
// baseline (915.281 us; speedup 1.0000x reference)
//
#include <hip/hip_runtime.h>
#include <hip/hip_bf16.h>
#include <stdint.h>

#define T_TOK 4096
#define HDIM  2048
#define IDIM  1408
#define NEXP  8
#define SIDIM 2816

typedef __bf16 bf16_t;
typedef __bf16 bf16x8 __attribute__((ext_vector_type(8)));
typedef __bf16 bf16x4 __attribute__((ext_vector_type(4)));
typedef float  f32x4  __attribute__((ext_vector_type(4)));

typedef uint32_t __attribute__((address_space(3))) lds_u32;
typedef uint32_t __attribute__((address_space(1))) glb_u32;

__device__ __forceinline__ void glds16(const bf16_t* g, const bf16_t* l) {
  __builtin_amdgcn_global_load_lds((const glb_u32*)g, (lds_u32*)l, 16, 0, 0);
}

// ---------------- convert x (f32 -> bf16) ----------------
__global__ void cvt_x_kernel(const float4* __restrict__ in, bf16x4* __restrict__ out, int n4) {
  int i = blockIdx.x * 256 + threadIdx.x;
  if (i >= n4) return;
  float4 v = in[i];
  bf16x4 o;
  o[0] = (bf16_t)v.x; o[1] = (bf16_t)v.y; o[2] = (bf16_t)v.z; o[3] = (bf16_t)v.w;
  out[i] = o;
}

// ---------------- transpose+convert: f32 [R][C] -> bf16 [C][R], batched in z ----------------
__global__ void tcvt_kernel(const float* __restrict__ in, bf16_t* __restrict__ out, int R, int C) {
  in  += (size_t)blockIdx.z * R * C;
  out += (size_t)blockIdx.z * R * C;
  __shared__ bf16_t t[64][72];            // stride 144B: 16B-aligned rows
  const int r0 = blockIdx.y * 64, c0 = blockIdx.x * 64;
  const int tid = threadIdx.x;
  const int cf4 = tid & 15;               // float4 col within tile
  const int rr  = tid >> 4;               // 0..15
#pragma unroll
  for (int s = 0; s < 4; ++s) {
    int r = rr + 16 * s;
    float4 v = *(const float4*)(in + (size_t)(r0 + r) * C + c0 + cf4 * 4);
    t[cf4 * 4 + 0][r] = (bf16_t)v.x;
    t[cf4 * 4 + 1][r] = (bf16_t)v.y;
    t[cf4 * 4 + 2][r] = (bf16_t)v.z;
    t[cf4 * 4 + 3][r] = (bf16_t)v.w;
  }
  __syncthreads();
  const int c  = tid >> 2;                // 0..63
  const int rb = (tid & 3) * 16;          // 0,16,32,48
  bf16x8 w0 = *(const bf16x8*)&t[c][rb];
  bf16x8 w1 = *(const bf16x8*)&t[c][rb + 8];
  bf16_t* op = out + (size_t)(c0 + c) * R + r0 + rb;
  *(bf16x8*)op = w0;
  *(bf16x8*)(op + 8) = w1;
}

// ---------------- router: one wave per token ----------------
__global__ void router_kernel(const float* __restrict__ x, const float* __restrict__ rw,
                              int* __restrict__ tk_i, float* __restrict__ tk_w,
                              int* __restrict__ counts) {
  int gtid = blockIdx.x * 256 + threadIdx.x;
  int t = gtid >> 6, lane = gtid & 63;
  const float4* xr = (const float4*)(x + (size_t)t * HDIM);
  float acc[NEXP];
#pragma unroll
  for (int e = 0; e < NEXP; e++) acc[e] = 0.f;
  for (int i = lane; i < HDIM / 4; i += 64) {
    float4 xv = xr[i];
#pragma unroll
    for (int e = 0; e < NEXP; e++) {
      float4 wv = ((const float4*)(rw + e * HDIM))[i];
      acc[e] += xv.x * wv.x + xv.y * wv.y + xv.z * wv.z + xv.w * wv.w;
    }
  }
#pragma unroll
  for (int e = 0; e < NEXP; e++)
#pragma unroll
    for (int off = 32; off; off >>= 1) acc[e] += __shfl_down(acc[e], off);
  if (lane == 0) {
    int i1 = 0; float m1 = acc[0];
#pragma unroll
    for (int e = 1; e < NEXP; e++) if (acc[e] > m1) { m1 = acc[e]; i1 = e; }
    int i2 = -1; float m2 = -1e30f;
#pragma unroll
    for (int e = 0; e < NEXP; e++) if (e != i1 && acc[e] > m2) { m2 = acc[e]; i2 = e; }
    float w1 = 1.f / (1.f + __expf(m2 - m1));   // == p1/(p1+p2) after softmax+renorm
    tk_i[t * 2] = i1; tk_i[t * 2 + 1] = i2;
    tk_w[t * 2] = w1; tk_w[t * 2 + 1] = 1.f - w1;
    atomicAdd(&counts[i1], 1); atomicAdd(&counts[i2], 1);
  }
}

__global__ void offs_kernel(const int* __restrict__ counts, int* __restrict__ offs) {
  if (threadIdx.x == 0 && blockIdx.x == 0) {
    int o = 0;
    for (int e = 0; e < NEXP; e++) { offs[e] = o; o += counts[e]; }
    offs[NEXP] = o;
  }
}

__global__ void scatter_kernel(const int* __restrict__ tk_i, const float* __restrict__ tk_w,
                               const int* __restrict__ offs, int* __restrict__ cursor,
                               int* __restrict__ tok_idx, float* __restrict__ tok_w) {
  int t = blockIdx.x * 256 + threadIdx.x;
  if (t >= T_TOK) return;
#pragma unroll
  for (int k = 0; k < 2; k++) {
    int e = tk_i[t * 2 + k];
    int pos = offs[e] + atomicAdd(&cursor[e], 1);
    tok_idx[pos] = t; tok_w[pos] = tk_w[t * 2 + k];
  }
}

// ---------------- fused gate/up GEMM + SwiGLU epilogue ----------------
// X:[*][K] bf16 (rows gathered if GATHER), GT/UT:[(e)][N][K] bf16, Hout:[slots][N] bf16
template <bool GATHER>
__global__ __launch_bounds__(256)
void gateup_kernel(const bf16_t* __restrict__ X, const bf16_t* __restrict__ GT,
                   const bf16_t* __restrict__ UT, const float* __restrict__ bg,
                   const float* __restrict__ bu, const int* __restrict__ offs,
                   const int* __restrict__ tok_idx, bf16_t* __restrict__ Hout,
                   int N, int K) {
  const int e = blockIdx.z;
  const int row0 = blockIdx.y * 128;
  int cnt, slot0;
  if (GATHER) {
    slot0 = offs[e];
    cnt = offs[e + 1] - slot0;
    if (row0 >= cnt) return;
  } else { cnt = T_TOK; slot0 = 0; }

  const bf16_t* Gp = GT + (size_t)e * N * K;
  const bf16_t* Up = UT + (size_t)e * N * K;

  __shared__ bf16_t sA[128 * 64];
  __shared__ bf16_t sG[128 * 64];
  __shared__ bf16_t sU[128 * 64];

  const int tid = threadIdx.x;
  const int wave = tid >> 6, lane = tid & 63;
  const int n0 = blockIdx.x * 128;

  const bf16_t* srcA[4]; const bf16_t* srcG[4]; const bf16_t* srcU[4];
  int ldsoff[4];
#pragma unroll
  for (int i = 0; i < 4; i++) {
    int c = wave * 4 + i;                 // 16 chunks of 8 rows
    int r = c * 8 + (lane >> 3);          // 0..127
    int kcol = (lane & 7) * 8;
    int arow;
    if (GATHER) {
      int rr = row0 + r; if (rr >= cnt) rr = cnt - 1;
      arow = tok_idx[slot0 + rr];
    } else arow = row0 + r;
    srcA[i] = X  + (size_t)arow * K + kcol;
    srcG[i] = Gp + (size_t)(n0 + r) * K + kcol;
    srcU[i] = Up + (size_t)(n0 + r) * K + kcol;
    ldsoff[i] = c * 1024;
  }

  f32x4 accg[4][4], accu[4][4];
#pragma unroll
  for (int mi = 0; mi < 4; mi++)
#pragma unroll
    for (int ni = 0; ni < 4; ni++) { accg[mi][ni] = (f32x4)(0.f); accu[mi][ni] = (f32x4)(0.f); }

  const int wr = wave >> 1, wc = wave & 1;
  const int lr = lane & 15, lg = lane >> 4;

  for (int kt = 0; kt < K / 64; ++kt) {
#pragma unroll
    for (int i = 0; i < 4; i++) {
      glds16(srcA[i], (const bf16_t*)((const char*)sA + ldsoff[i]));
      glds16(srcG[i], (const bf16_t*)((const char*)sG + ldsoff[i]));
      glds16(srcU[i], (const bf16_t*)((const char*)sU + ldsoff[i]));
      srcA[i] += 64; srcG[i] += 64; srcU[i] += 64;
    }
    __syncthreads();
#pragma unroll
    for (int ks = 0; ks < 2; ++ks) {
      bf16x8 af[4];
#pragma unroll
      for (int mi = 0; mi < 4; mi++)
        af[mi] = *(const bf16x8*)&sA[(wr * 64 + mi * 16 + lr) * 64 + ks * 32 + lg * 8];
#pragma unroll
      for (int ni = 0; ni < 4; ni++) {
        bf16x8 gf = *(const bf16x8*)&sG[(wc * 64 + ni * 16 + lr) * 64 + ks * 32 + lg * 8];
        bf16x8 uf = *(const bf16x8*)&sU[(wc * 64 + ni * 16 + lr) * 64 + ks * 32 + lg * 8];
#pragma unroll
        for (int mi = 0; mi < 4; mi++)
          accg[mi][ni] = __builtin_amdgcn_mfma_f32_16x16x32_bf16(af[mi], gf, accg[mi][ni], 0, 0, 0);
#pragma unroll
        for (int mi = 0; mi < 4; mi++)
          accu[mi][ni] = __builtin_amdgcn_mfma_f32_16x16x32_bf16(af[mi], uf, accu[mi][ni], 0, 0, 0);
      }
    }
    __syncthreads();
  }

#pragma unroll
  for (int mi = 0; mi < 4; mi++) {
#pragma unroll
    for (int j = 0; j < 4; j++) {
      int rl = wr * 64 + mi * 16 + lg * 4 + j;
      int grow = row0 + rl;
      if (GATHER && grow >= cnt) continue;
      size_t orow = (size_t)(slot0 + grow) * N;
#pragma unroll
      for (int ni = 0; ni < 4; ni++) {
        int col = n0 + wc * 64 + ni * 16 + lr;
        float g = accg[mi][ni][j];
        float u = accu[mi][ni][j];
        if (!GATHER) { g += bg[col]; u += bu[col]; }
        float h = (g / (1.f + __expf(-g))) * u;   // silu(g) * u
        Hout[orow + col] = (bf16_t)h;
      }
    }
  }
}

// ---------------- down-projection GEMM ----------------
// Hin:[slots][K] bf16, DT:[(e)][HDIM][K] bf16.
// GATHER: atomicAdd(out[tok][col], w*acc).  !GATHER: out[row][col] = acc + bias[col].
template <bool GATHER>
__global__ __launch_bounds__(256)
void down_kernel(const bf16_t* __restrict__ Hin, const bf16_t* __restrict__ DT,
                 const float* __restrict__ bias, const int* __restrict__ offs,
                 const int* __restrict__ tok_idx, const float* __restrict__ tok_w,
                 float* __restrict__ out, int K) {
  const int N = HDIM;
  const int e = blockIdx.z;
  const int row0 = blockIdx.y * 128;
  int cnt, slot0;
  if (GATHER) {
    slot0 = offs[e];
    cnt = offs[e + 1] - slot0;
    if (row0 >= cnt) return;
  } else { cnt = T_TOK; slot0 = 0; }

  const bf16_t* Dp = DT + (size_t)e * N * K;

  __shared__ bf16_t sA[128 * 64];
  __shared__ bf16_t sB[128 * 64];

  const int tid = threadIdx.x;
  const int wave = tid >> 6, lane = tid & 63;
  const int n0 = blockIdx.x * 128;

  const bf16_t* srcA[4]; const bf16_t* srcB[4];
  int ldsoff[4];
#pragma unroll
  for (int i = 0; i < 4; i++) {
    int c = wave * 4 + i;
    int r = c * 8 + (lane >> 3);
    int kcol = (lane & 7) * 8;
    int rr = row0 + r;
    if (GATHER && rr >= cnt) rr = cnt - 1;
    srcA[i] = Hin + (size_t)(slot0 + rr) * K + kcol;
    srcB[i] = Dp + (size_t)(n0 + r) * K + kcol;
    ldsoff[i] = c * 1024;
  }

  f32x4 acc[4][4];
#pragma unroll
  for (int mi = 0; mi < 4; mi++)
#pragma unroll
    for (int ni = 0; ni < 4; ni++) acc[mi][ni] = (f32x4)(0.f);

  const int wr = wave >> 1, wc = wave & 1;
  const int lr = lane & 15, lg = lane >> 4;

  for (int kt = 0; kt < K / 64; ++kt) {
#pragma unroll
    for (int i = 0; i < 4; i++) {
      glds16(srcA[i], (const bf16_t*)((const char*)sA + ldsoff[i]));
      glds16(srcB[i], (const bf16_t*)((const char*)sB + ldsoff[i]));
      srcA[i] += 64; srcB[i] += 64;
    }
    __syncthreads();
#pragma unroll
    for (int ks = 0; ks < 2; ++ks) {
      bf16x8 af[4];
#pragma unroll
      for (int mi = 0; mi < 4; mi++)
        af[mi] = *(const bf16x8*)&sA[(wr * 64 + mi * 16 + lr) * 64 + ks * 32 + lg * 8];
#pragma unroll
      for (int ni = 0; ni < 4; ni++) {
        bf16x8 bfrag = *(const bf16x8*)&sB[(wc * 64 + ni * 16 + lr) * 64 + ks * 32 + lg * 8];
#pragma unroll
        for (int mi = 0; mi < 4; mi++)
          acc[mi][ni] = __builtin_amdgcn_mfma_f32_16x16x32_bf16(af[mi], bfrag, acc[mi][ni], 0, 0, 0);
      }
    }
    __syncthreads();
  }

#pragma unroll
  for (int mi = 0; mi < 4; mi++) {
#pragma unroll
    for (int j = 0; j < 4; j++) {
      int rl = wr * 64 + mi * 16 + lg * 4 + j;
      int grow = row0 + rl;
      if (GATHER && grow >= cnt) continue;
      if (GATHER) {
        int slot = slot0 + grow;
        int tokn = tok_idx[slot];
        float w = tok_w[slot];
#pragma unroll
        for (int ni = 0; ni < 4; ni++) {
          int col = n0 + wc * 64 + ni * 16 + lr;
          atomicAdd(&out[(size_t)tokn * N + col], w * acc[mi][ni][j]);
        }
      } else {
#pragma unroll
        for (int ni = 0; ni < 4; ni++) {
          int col = n0 + wc * 64 + ni * 16 + lr;
          out[(size_t)grow * N + col] = acc[mi][ni][j] + bias[col];
        }
      }
    }
  }
}

extern "C" void kernel_launch(void* const* d_in, const int* in_sizes, int n_in,
                              void* d_out, int out_size, void* d_ws, size_t ws_size,
                              hipStream_t stream) {
  const float* x_f  = (const float*)d_in[0];
  const float* rw   = (const float*)d_in[1];
  const float* gate = (const float*)d_in[2];
  const float* up   = (const float*)d_in[3];
  const float* down = (const float*)d_in[4];
  const float* sgw  = (const float*)d_in[5];
  const float* sgb  = (const float*)d_in[6];
  const float* suw  = (const float*)d_in[7];
  const float* sub  = (const float*)d_in[8];
  const float* sdw  = (const float*)d_in[9];
  const float* sdb  = (const float*)d_in[10];
  float* out = (float*)d_out;

  char* ws = (char*)d_ws;
  size_t off = 0;
  auto alloc = [&](size_t bytes) {
    char* p = ws + off;
    off += (bytes + 255) & ~(size_t)255;
    return p;
  };
  bf16_t* xb    = (bf16_t*)alloc((size_t)T_TOK * HDIM * 2);
  bf16_t* gT    = (bf16_t*)alloc((size_t)NEXP * IDIM * HDIM * 2);
  bf16_t* uT    = (bf16_t*)alloc((size_t)NEXP * IDIM * HDIM * 2);
  bf16_t* dT    = (bf16_t*)alloc((size_t)NEXP * HDIM * IDIM * 2);
  bf16_t* sgT   = (bf16_t*)alloc((size_t)SIDIM * HDIM * 2);
  bf16_t* suT   = (bf16_t*)alloc((size_t)SIDIM * HDIM * 2);
  bf16_t* sdT   = (bf16_t*)alloc((size_t)HDIM * SIDIM * 2);
  bf16_t* hid_r = (bf16_t*)alloc((size_t)T_TOK * 2 * IDIM * 2);
  bf16_t* hid_s = (bf16_t*)alloc((size_t)T_TOK * SIDIM * 2);
  int*    meta  = (int*)alloc(128);
  int*    tok_idx = (int*)alloc(8192 * 4);
  float*  tok_w   = (float*)alloc(8192 * 4);
  int*    tk_i    = (int*)alloc((size_t)T_TOK * 2 * 4);
  float*  tk_w2   = (float*)alloc((size_t)T_TOK * 2 * 4);

  int* counts = meta;
  int* cursor = meta + 8;
  int* offs   = meta + 16;

  hipMemsetAsync(meta, 0, 128, stream);

  cvt_x_kernel<<<(T_TOK * HDIM / 4) / 256, 256, 0, stream>>>(
      (const float4*)x_f, (bf16x4*)xb, T_TOK * HDIM / 4);

  tcvt_kernel<<<dim3(IDIM / 64, HDIM / 64, NEXP), 256, 0, stream>>>(gate, gT, HDIM, IDIM);
  tcvt_kernel<<<dim3(IDIM / 64, HDIM / 64, NEXP), 256, 0, stream>>>(up,   uT, HDIM, IDIM);
  tcvt_kernel<<<dim3(HDIM / 64, IDIM / 64, NEXP), 256, 0, stream>>>(down, dT, IDIM, HDIM);
  tcvt_kernel<<<dim3(SIDIM / 64, HDIM / 64, 1), 256, 0, stream>>>(sgw, sgT, HDIM, SIDIM);
  tcvt_kernel<<<dim3(SIDIM / 64, HDIM / 64, 1), 256, 0, stream>>>(suw, suT, HDIM, SIDIM);
  tcvt_kernel<<<dim3(HDIM / 64, SIDIM / 64, 1), 256, 0, stream>>>(sdw, sdT, SIDIM, HDIM);

  router_kernel<<<T_TOK / 4, 256, 0, stream>>>(x_f, rw, tk_i, tk_w2, counts);
  offs_kernel<<<1, 64, 0, stream>>>(counts, offs);
  scatter_kernel<<<T_TOK / 256, 256, 0, stream>>>(tk_i, tk_w2, offs, cursor, tok_idx, tok_w);

  gateup_kernel<true><<<dim3(IDIM / 128, T_TOK / 128, NEXP), 256, 0, stream>>>(
      xb, gT, uT, nullptr, nullptr, offs, tok_idx, hid_r, IDIM, HDIM);
  gateup_kernel<false><<<dim3(SIDIM / 128, T_TOK / 128, 1), 256, 0, stream>>>(
      xb, sgT, suT, sgb, sub, nullptr, nullptr, hid_s, SIDIM, HDIM);

  // shared-down WRITES out (runs first), routed-down atomically accumulates.
  down_kernel<false><<<dim3(HDIM / 128, T_TOK / 128, 1), 256, 0, stream>>>(
      hid_s, sdT, sdb, nullptr, nullptr, nullptr, out, SIDIM);
  down_kernel<true><<<dim3(HDIM / 128, T_TOK / 128, NEXP), 256, 0, stream>>>(
      hid_r, dT, nullptr, offs, tok_idx, tok_w, out, IDIM);
}